// Round 1
// baseline (166.115 us; speedup 1.0000x reference)
//
#include <hip/hip_runtime.h>
#include <math.h>

#define NSAMP 32
#define MFEAT 30
#define XPAD  36                 // LDS row stride in floats: 144 B, 16B-aligned, breaks power-of-2 bank aliasing
#define SQRT3 1.7320508075688772f

__device__ __forceinline__ float rdlane(float v, int l) {
    return __int_as_float(__builtin_amdgcn_readlane(__float_as_int(v), l));
}

__global__ __launch_bounds__(64) void tmk_kernel(
    const float* __restrict__ aug,     // (32, n_loc, 31)
    const float* __restrict__ scales,  // (n_loc)
    const float* __restrict__ nug,     // (n_loc)
    const float* __restrict__ frac,    // (1)
    const int*   __restrict__ bidx,    // (n_loc)
    const float* __restrict__ thq,     // (1)
    const float* __restrict__ sigp,    // (2)
    const float* __restrict__ lens,    // (1)
    float* __restrict__ out,
    int n_loc)
{
    __shared__ __align__(16) float X[NSAMP * XPAD];
    __shared__ __align__(16) float A[NSAMP * XPAD];
    __shared__ float SQ[NSAMP];

    const int loc  = blockIdx.x;
    const int lane = threadIdx.x;
    if (loc >= n_loc) return;

    // ---- uniform scalars ----
    const float a_s   = -0.5f * __expf(thq[0]);            // -0.5*exp(theta_q)
    const float invls = 1.0f / (__expf(lens[0]) * SQRT3);  // 1/(exp(ls)*sqrt(2*SMOOTH))

    // ---- load + scale features into LDS: X[s][k] = nan_to_0(aug[s,loc,1+k]) * exp(a_s*(k+1)) * invls ----
    {
        const float* bp = aug + (size_t)loc * 31 + 1;
        const size_t srow = (size_t)n_loc * 31;
#pragma unroll
        for (int it = 0; it < 15; ++it) {            // 15*64 = 960 = 32*30
            int t = lane + it * 64;
            int s = t / MFEAT;
            int k = t - s * MFEAT;
            float v = bp[(size_t)s * srow + k];
            v = (v != v) ? 0.0f : v;                 // isnan -> 0
            float sc = __expf(a_s * (float)(k + 1)) * invls;
            X[s * XPAD + k] = v * sc;
        }
        // zero-pad cols 30,31 so float4 chunk 7 reads zeros
        int s = lane & 31, kk = MFEAT + (lane >> 5);
        X[s * XPAD + kk] = 0.0f;
    }
    __syncthreads();

    // ---- per-lane column j in registers + squared norms ----
    const int j  = lane & 31;
    const int ih = lane >> 5;                         // 0 or 1: row parity handled by each half-wave
    float xc[32];
#pragma unroll
    for (int c = 0; c < 8; ++c) {
        float4 v = *reinterpret_cast<const float4*>(&X[j * XPAD + 4 * c]);
        xc[4 * c + 0] = v.x; xc[4 * c + 1] = v.y;
        xc[4 * c + 2] = v.z; xc[4 * c + 3] = v.w;
    }
    float sq_own;
    {
        float s0 = 0.f, s1 = 0.f, s2 = 0.f, s3 = 0.f;
#pragma unroll
        for (int c = 0; c < 8; ++c) {
            s0 = fmaf(xc[4 * c + 0], xc[4 * c + 0], s0);
            s1 = fmaf(xc[4 * c + 1], xc[4 * c + 1], s1);
            s2 = fmaf(xc[4 * c + 2], xc[4 * c + 2], s2);
            s3 = fmaf(xc[4 * c + 3], xc[4 * c + 3], s3);
        }
        sq_own = (s0 + s1) + (s2 + s3);
    }
    if (lane < 32) SQ[j] = sq_own;
    __syncthreads();

    // ---- per-location coefficient ----
    const float fr  = frac[0];
    const float sp0 = sigp[0], sp1 = sigp[1];
    const float scl = scales[loc];
    const float nm  = nug[loc];
    const float sig = __expf(sp0 + sp1 * __logf(scl));
    const float coef = fr * sig * sig / nm;
    const bool  bz   = (bidx[loc] == 0);
    const float sqj  = sq_own;

    // ---- Gram + matern epilogue; store g (coalesced) and mirror into LDS A ----
    const size_t gbase = (size_t)loc * 1024;
    float* gout = out + gbase;
#pragma unroll
    for (int r = 0; r < 16; ++r) {
        const int i = 2 * r + ih;
        float a0 = 0.f, a1 = 0.f, a2 = 0.f, a3 = 0.f;
#pragma unroll
        for (int c = 0; c < 8; ++c) {
            float4 v = *reinterpret_cast<const float4*>(&X[i * XPAD + 4 * c]); // broadcast read
            a0 = fmaf(v.x, xc[4 * c + 0], a0);
            a1 = fmaf(v.y, xc[4 * c + 1], a1);
            a2 = fmaf(v.z, xc[4 * c + 2], a2);
            a3 = fmaf(v.w, xc[4 * c + 3], a3);
        }
        float dot = (a0 + a1) + (a2 + a3);
        float d2  = fmaxf(SQ[i] + sqj - 2.f * dot, 0.f);
        float s3d = SQRT3 * sqrtf(d2);
        float nl  = (1.f + s3d) * __expf(-s3d);
        float gv  = fmaf(coef, nl, (i == j) ? 1.f : 0.f);
        if (bz) gv = (i == j) ? 1.f : 0.f;
        gout[64 * r + lane] = gv;       // == gout[i*32 + j], fully coalesced
        A[i * XPAD + j] = gv;
    }
    __syncthreads();

    // ---- register Cholesky: lane i owns row i (lanes 32..63 duplicate, harmless) ----
    float av[32];
#pragma unroll
    for (int c = 0; c < 8; ++c) {
        float4 v = *reinterpret_cast<const float4*>(&A[j * XPAD + 4 * c]);
        av[4 * c + 0] = v.x; av[4 * c + 1] = v.y;
        av[4 * c + 2] = v.z; av[4 * c + 3] = v.w;
    }
#pragma unroll
    for (int k = 0; k < 32; ++k) {
        float dinv = 1.0f / sqrtf(rdlane(av[k], k));   // broadcast diag
        float lik  = av[k] * dinv;                     // L[i][k] (valid for i>=k)
        av[k] = lik;
#pragma unroll
        for (int jj = k + 1; jj < 32; ++jj) {
            av[jj] = fmaf(-lik, rdlane(lik, jj), av[jj]);  // A[i][jj] -= L[i][k]*L[jj][k]
        }
    }
    __syncthreads();   // A reads above are done (in-order wave); fence before overwrite

    // ---- write masked L rows back to LDS, then coalesced store ----
    if (lane < 32) {
#pragma unroll
        for (int c = 0; c < 8; ++c) {
            float4 w;
            w.x = (4 * c + 0 <= j) ? av[4 * c + 0] : 0.f;
            w.y = (4 * c + 1 <= j) ? av[4 * c + 1] : 0.f;
            w.z = (4 * c + 2 <= j) ? av[4 * c + 2] : 0.f;
            w.w = (4 * c + 3 <= j) ? av[4 * c + 3] : 0.f;
            *reinterpret_cast<float4*>(&A[j * XPAD + 4 * c]) = w;
        }
    }
    __syncthreads();

    float* lout = out + (size_t)n_loc * 1024 + gbase;
#pragma unroll
    for (int r = 0; r < 16; ++r) {
        lout[64 * r + lane] = A[(2 * r + ih) * XPAD + j];
    }

    if (lane == 0) out[(size_t)n_loc * 2048 + loc] = nm;
}

extern "C" void kernel_launch(void* const* d_in, const int* in_sizes, int n_in,
                              void* d_out, int out_size, void* d_ws, size_t ws_size,
                              hipStream_t stream) {
    const float* aug    = (const float*)d_in[0];
    const float* scales = (const float*)d_in[1];
    const float* nug    = (const float*)d_in[2];
    const float* frac   = (const float*)d_in[3];
    const int*   bidx   = (const int*)  d_in[4];
    const float* thq    = (const float*)d_in[5];
    const float* sigp   = (const float*)d_in[6];
    const float* lens   = (const float*)d_in[7];
    const int n_loc = in_sizes[1];

    tmk_kernel<<<n_loc, 64, 0, stream>>>(aug, scales, nug, frac, bidx, thq,
                                         sigp, lens, (float*)d_out, n_loc);
}